// Round 5
// baseline (863.761 us; speedup 1.0000x reference)
//
#include <hip/hip_runtime.h>

#define NE   8
#define DIN  4096
#define DOUT 4096
#define TOK  8192

// fast-path tile: 128x128, BK=32, ring-4 LDS pipeline
#define BM 128
#define BN 128
#define BK 32
#define NT (DIN / BK)       // 128 K-steps
#define BUFE (BM * BK)      // 4096 bf16 elems per operand buffer (8 KB)

// legacy fallback tile
#define FBM 128
#define FBK 32
#define LDSK 40

typedef __attribute__((ext_vector_type(4))) float f32x4;
typedef __attribute__((ext_vector_type(8))) short bf16x8;
typedef __attribute__((ext_vector_type(2))) unsigned long long u64x2;

#define AS1 __attribute__((address_space(1)))
#define AS3 __attribute__((address_space(3)))

static __device__ __forceinline__ unsigned short f2bf(float f) {
  unsigned u = __builtin_bit_cast(unsigned, f);
  u += 0x7fffu + ((u >> 16) & 1u);   // RTNE
  return (unsigned short)(u >> 16);
}

static __device__ __forceinline__ unsigned long long pack4(f32x4 v) {
  return (unsigned long long)f2bf(v[0])
       | ((unsigned long long)f2bf(v[1]) << 16)
       | ((unsigned long long)f2bf(v[2]) << 32)
       | ((unsigned long long)f2bf(v[3]) << 48);
}

static __device__ __forceinline__ void gload16(const void* g, void* l) {
  __builtin_amdgcn_global_load_lds((const AS1 unsigned int*)g,
                                   (AS3 unsigned int*)l, 16, 0, 0);
}

// ---------- fused gating (fp32-exact) + x -> bf16 conversion ----------
__global__ void gate_convert(const float* __restrict__ x, const float* __restrict__ gw,
                             const float* __restrict__ gb, int* __restrict__ counts,
                             int* __restrict__ tlist, unsigned short* __restrict__ xbf) {
  const int lane = threadIdx.x & 63;
  const int tok  = blockIdx.x * 4 + (threadIdx.x >> 6);
  const float* xr = x + (size_t)tok * DIN;
  unsigned short* xo = xbf + (size_t)tok * DIN;
  float acc[NE];
  #pragma unroll
  for (int e = 0; e < NE; ++e) acc[e] = 0.f;
  for (int i = lane * 4; i < DIN; i += 256) {
    f32x4 xv = *(const f32x4*)(xr + i);
    *(unsigned long long*)(xo + i) = pack4(xv);
    #pragma unroll
    for (int e = 0; e < NE; ++e) {
      f32x4 wv = *(const f32x4*)(gw + e * DIN + i);
      acc[e] += xv[0]*wv[0] + xv[1]*wv[1] + xv[2]*wv[2] + xv[3]*wv[3];
    }
  }
  #pragma unroll
  for (int e = 0; e < NE; ++e) {
    float v = acc[e];
    #pragma unroll
    for (int o = 32; o > 0; o >>= 1) v += __shfl_xor(v, o);
    acc[e] = v;
  }
  if (lane == 0) {
    float bv = acc[0] + gb[0];
    int best = 0;
    #pragma unroll
    for (int e = 1; e < NE; ++e) {
      float v = acc[e] + gb[e];
      if (v > bv) { bv = v; best = e; }   // strict > == numpy first-max
    }
    int pos = atomicAdd(&counts[best], 1);
    tlist[best * TOK + pos] = tok;
  }
}

// ---------- expert weights fp32 -> bf16 ----------
__global__ void convw(const float* __restrict__ w, unsigned short* __restrict__ wbf) {
  const size_t n = (size_t)NE * DOUT * DIN;
  size_t idx = ((size_t)blockIdx.x * 256 + threadIdx.x) * 8;
  const size_t stride = (size_t)gridDim.x * 256 * 8;
  for (; idx < n; idx += stride) {
    f32x4 a = *(const f32x4*)(w + idx);
    f32x4 b = *(const f32x4*)(w + idx + 4);
    u64x2 v; v[0] = pack4(a); v[1] = pack4(b);
    *(u64x2*)(wbf + idx) = v;
  }
}

// ---------- fast grouped GEMM: 128x128, BK=32, ring-4, counted vmcnt ----------
// Pipeline invariants (hand-verified):
//   compute(t) reads buf[t&3] = tile t, staged at step t-3, guaranteed landed
//     by vmcnt(8) at end of step t-1 (outstanding there = stages of steps t-1,t-2).
//   stage(t) writes buf[(t+3)&3] = buf[(t-1)&3], whose readers all passed the
//     end-of-step-(t-1) barrier (their ds_reads completed via MFMA lgkm deps).
//   vmcnt never drains to 0 in the main loop; ONE barrier per step.
__global__ __launch_bounds__(256, 2)
void moe_gemm_bf(const unsigned short* __restrict__ xbf,
                 const unsigned short* __restrict__ wbf,
                 const float* __restrict__ eb,
                 const int* __restrict__ counts,
                 const int* __restrict__ tlist,
                 float* __restrict__ out) {
  __shared__ unsigned short sA[4][BUFE];   // 32 KB
  __shared__ unsigned short sB[4][BUFE];   // 32 KB
  __shared__ int rowtok[BM];

  const int tid = threadIdx.x;

  // XCD-chunked bijective swizzle: 2304 blocks = 8 * 288; slot-major so each
  // XCD runs complete n-sweeps of a few slots (A-panel 1MB stays L2-resident)
  const int cpx  = gridDim.x >> 3;
  const int wgid = ((int)blockIdx.x & 7) * cpx + ((int)blockIdx.x >> 3);
  const int ntile = wgid & 31;
  const int slot  = wgid >> 5;

  int e = -1, mtile = 0, Me = 0;
  {
    int accn = 0;
    #pragma unroll
    for (int j = 0; j < NE; ++j) {
      int c = counts[j];
      int tt = (c + BM - 1) / BM;
      if (e < 0 && slot < accn + tt) { e = j; mtile = slot - accn; Me = c; }
      accn += tt;
    }
  }
  if (e < 0) return;

  const int n0 = ntile * BN;
  const int m0 = mtile * BM;
  const unsigned short* wbase = wbf + (size_t)e * DOUT * DIN;

  if (tid < BM) {
    int r = m0 + tid;
    rowtok[tid] = tlist[e * TOK + (r < Me ? r : Me - 1)];
  }
  __syncthreads();

  const int w = tid >> 6, l = tid & 63;

  // ---- staging geometry: operand chunk = 128 rows x 32 cols (8 KB) = 2 issues
  // thread -> (row srow / srow+64, 16B slot sslot); source col pre-swizzled by
  // involution f(r) = (r&3)^((r>>2)&3)  [f(r)==f(r+64), so one colsw/thread]
  const int srow  = tid >> 2;          // 0..63
  const int sslot = tid & 3;
  const int fs    = (srow & 3) ^ ((srow >> 2) & 3);
  const int colsw = (sslot ^ fs) * 8;  // elems

  const unsigned short* ga0 = xbf   + (size_t)rowtok[srow]      * DIN + colsw;
  const unsigned short* ga1 = xbf   + (size_t)rowtok[srow + 64] * DIN + colsw;
  const unsigned short* gb0 = wbase + (size_t)(n0 + srow)       * DIN + colsw;
  const unsigned short* gb1 = wbase + (size_t)(n0 + srow + 64)  * DIN + colsw;
  const int ldsb = w * 512;            // wave-uniform base within a 4KB half

  // ---- frag geometry: 4 waves as 2x2, per-wave 64x64 out
  const int wr = (w >> 1) * 64;
  const int wc = (w & 1) * 64;
  const int lr = l & 15, lk = l >> 4;
  int offA[4], offB[4];
  #pragma unroll
  for (int m = 0; m < 4; ++m) {
    int r = wr + m * 16 + lr;
    offA[m] = r * BK + ((lk ^ ((r & 3) ^ ((r >> 2) & 3))) * 8);
  }
  #pragma unroll
  for (int n = 0; n < 4; ++n) {
    int r = wc + n * 16 + lr;
    offB[n] = r * BK + ((lk ^ ((r & 3) ^ ((r >> 2) & 3))) * 8);
  }

  f32x4 acc[4][4];
  #pragma unroll
  for (int m = 0; m < 4; ++m)
    #pragma unroll
    for (int n = 0; n < 4; ++n) acc[m][n] = (f32x4){0.f, 0.f, 0.f, 0.f};

#define STAGE(kt, b) do {                                   \
    const int ko_ = (kt) * BK;                              \
    gload16(ga0 + ko_, &sA[b][ldsb]);                       \
    gload16(ga1 + ko_, &sA[b][2048 + ldsb]);                \
    gload16(gb0 + ko_, &sB[b][ldsb]);                       \
    gload16(gb1 + ko_, &sB[b][2048 + ldsb]);                \
  } while (0)

  // prologue: tiles 0,1,2 in flight (12 loads); vmcnt(8) => tile 0 landed
  STAGE(0, 0);
  STAGE(1, 1);
  STAGE(2, 2);
  asm volatile("s_waitcnt vmcnt(8)" ::: "memory");
  __builtin_amdgcn_s_barrier();
  asm volatile("" ::: "memory");

  for (int t = 0; t < NT; ++t) {
    const int bc = t & 3;
    const int ts = (t + 3 < NT) ? t + 3 : NT - 1;   // clamped tail: never read
    const int bs = (t + 3) & 3;
    STAGE(ts, bs);

    bf16x8 av[4], bv[4];
    #pragma unroll
    for (int m = 0; m < 4; ++m) av[m] = *(const bf16x8*)&sA[bc][offA[m]];
    #pragma unroll
    for (int n = 0; n < 4; ++n) bv[n] = *(const bf16x8*)&sB[bc][offB[n]];

    __builtin_amdgcn_s_setprio(1);
    #pragma unroll
    for (int m = 0; m < 4; ++m)
      #pragma unroll
      for (int n = 0; n < 4; ++n)
        acc[m][n] = __builtin_amdgcn_mfma_f32_16x16x32_bf16(av[m], bv[n], acc[m][n], 0, 0, 0);
    __builtin_amdgcn_s_setprio(0);

    asm volatile("s_waitcnt vmcnt(8)" ::: "memory");   // tile t+1 landed; t+2,t+3 in flight
    __builtin_amdgcn_s_barrier();
    asm volatile("" ::: "memory");
  }

  // epilogue: bias + guarded scatter (C/D: col = lane&15, row = (lane>>4)*4 + j)
  float bias[4];
  #pragma unroll
  for (int n = 0; n < 4; ++n) bias[n] = eb[e * DOUT + n0 + wc + n * 16 + lr];

  #pragma unroll
  for (int m = 0; m < 4; ++m) {
    #pragma unroll
    for (int j = 0; j < 4; ++j) {
      int rloc = wr + m * 16 + lk * 4 + j;
      if (m0 + rloc < Me) {
        int tokr = rowtok[rloc];
        float* op = out + (size_t)tokr * DOUT + n0 + wc;
        #pragma unroll
        for (int n = 0; n < 4; ++n)
          op[n * 16 + lr] = acc[m][n][j] + bias[n];
      }
    }
  }
#undef STAGE
}

// ================= legacy fallback (fp32 direct, used only if ws too small) ==========
__global__ void gate_kernel(const float* __restrict__ x, const float* __restrict__ gw,
                            const float* __restrict__ gb, int* __restrict__ counts,
                            int* __restrict__ tlist) {
  const int lane = threadIdx.x & 63;
  const int tok  = blockIdx.x * 4 + (threadIdx.x >> 6);
  const float* xr = x + (size_t)tok * DIN;
  float acc[NE];
  #pragma unroll
  for (int e = 0; e < NE; ++e) acc[e] = 0.f;
  for (int i = lane; i < DIN; i += 64) {
    float xv = xr[i];
    #pragma unroll
    for (int e = 0; e < NE; ++e) acc[e] += xv * gw[e * DIN + i];
  }
  #pragma unroll
  for (int e = 0; e < NE; ++e) {
    float v = acc[e];
    #pragma unroll
    for (int o = 32; o > 0; o >>= 1) v += __shfl_xor(v, o);
    acc[e] = v;
  }
  if (lane == 0) {
    float bv = acc[0] + gb[0];
    int best = 0;
    #pragma unroll
    for (int e = 1; e < NE; ++e) {
      float v = acc[e] + gb[e];
      if (v > bv) { bv = v; best = e; }
    }
    int pos = atomicAdd(&counts[best], 1);
    tlist[best * TOK + pos] = tok;
  }
}

__global__ __launch_bounds__(256, 2)
void moe_gemm(const float* __restrict__ x, const float* __restrict__ ew,
              const float* __restrict__ eb, const int* __restrict__ counts,
              const int* __restrict__ tlist, float* __restrict__ out) {
  __shared__ unsigned short fA[2][FBM * LDSK];
  __shared__ unsigned short fB[2][FBM * LDSK];
  __shared__ int rowtok[FBM];

  const int tid  = threadIdx.x;
  const int slot = blockIdx.y;

  int e = -1, mtile = 0, Me = 0;
  {
    int acc = 0;
    #pragma unroll
    for (int j = 0; j < NE; ++j) {
      int c = counts[j];
      int t = (c + FBM - 1) / FBM;
      if (e < 0 && slot < acc + t) { e = j; mtile = slot - acc; Me = c; }
      acc += t;
    }
  }
  if (e < 0) return;

  const int n0 = blockIdx.x * FBM;
  const int m0 = mtile * FBM;
  const float* we = ew + (size_t)e * DOUT * DIN;

  if (tid < FBM) {
    int r = m0 + tid;
    rowtok[tid] = tlist[e * TOK + (r < Me ? r : Me - 1)];
  }
  __syncthreads();

  const int srow = tid >> 3;
  const int scol = (tid & 7) * 4;
  const int lane = tid & 63;
  const int w  = tid >> 6;
  const int wr = (w >> 1) * 64;
  const int wc = (w & 1) * 64;
  const int lr = lane & 15;
  const int lk = lane >> 4;

  f32x4 accf[4][4];
  #pragma unroll
  for (int m = 0; m < 4; ++m)
    #pragma unroll
    for (int n = 0; n < 4; ++n) accf[m][n] = (f32x4){0.f, 0.f, 0.f, 0.f};

  const float* aptr[4];
  const float* bptr[4];
  #pragma unroll
  for (int p = 0; p < 4; ++p) {
    int r = p * 32 + srow;
    aptr[p] = x  + (size_t)rowtok[r] * DIN + scol;
    bptr[p] = we + (size_t)(n0 + r)  * DIN + scol;
  }

  #pragma unroll
  for (int p = 0; p < 4; ++p) {
    int r = p * 32 + srow;
    *(unsigned long long*)&fA[0][r * LDSK + scol] = pack4(*(const f32x4*)(aptr[p]));
    *(unsigned long long*)&fB[0][r * LDSK + scol] = pack4(*(const f32x4*)(bptr[p]));
  }
  __syncthreads();

  int cur = 0;
  for (int kt = 0; kt < DIN / FBK; ++kt) {
    f32x4 ra[4], rb[4];
    const bool more = (kt + 1 < DIN / FBK);
    if (more) {
      const int koff = (kt + 1) * FBK;
      #pragma unroll
      for (int p = 0; p < 4; ++p) {
        ra[p] = *(const f32x4*)(aptr[p] + koff);
        rb[p] = *(const f32x4*)(bptr[p] + koff);
      }
    }
    bf16x8 af[4], bfr[4];
    #pragma unroll
    for (int m = 0; m < 4; ++m)
      af[m] = *(const bf16x8*)&fA[cur][(wr + m * 16 + lr) * LDSK + lk * 8];
    #pragma unroll
    for (int n = 0; n < 4; ++n)
      bfr[n] = *(const bf16x8*)&fB[cur][(wc + n * 16 + lr) * LDSK + lk * 8];
    #pragma unroll
    for (int m = 0; m < 4; ++m)
      #pragma unroll
      for (int n = 0; n < 4; ++n)
        accf[m][n] = __builtin_amdgcn_mfma_f32_16x16x32_bf16(af[m], bfr[n], accf[m][n], 0, 0, 0);
    if (more) {
      #pragma unroll
      for (int p = 0; p < 4; ++p) {
        int r = p * 32 + srow;
        *(unsigned long long*)&fA[cur ^ 1][r * LDSK + scol] = pack4(ra[p]);
        *(unsigned long long*)&fB[cur ^ 1][r * LDSK + scol] = pack4(rb[p]);
      }
    }
    __syncthreads();
    cur ^= 1;
  }

  float bias[4];
  #pragma unroll
  for (int n = 0; n < 4; ++n) bias[n] = eb[e * DOUT + n0 + wc + n * 16 + lr];

  #pragma unroll
  for (int m = 0; m < 4; ++m) {
    #pragma unroll
    for (int j = 0; j < 4; ++j) {
      int rloc = wr + m * 16 + lk * 4 + j;
      if (m0 + rloc < Me) {
        int tokr = rowtok[rloc];
        float* op = out + (size_t)tokr * DOUT + n0 + wc;
        #pragma unroll
        for (int n = 0; n < 4; ++n)
          op[n * 16 + lr] = accf[m][n][j] + bias[n];
      }
    }
  }
}

extern "C" void kernel_launch(void* const* d_in, const int* in_sizes, int n_in,
                              void* d_out, int out_size, void* d_ws, size_t ws_size,
                              hipStream_t stream) {
  const float* x  = (const float*)d_in[0];
  const float* gw = (const float*)d_in[1];
  const float* gb = (const float*)d_in[2];
  const float* ew = (const float*)d_in[3];
  const float* eb = (const float*)d_in[4];
  float* out = (float*)d_out;

  // ws layout: counts[16] | tlist[8*8192] | @1MB xbf (64MB) | wbf (256MB)
  int* counts = (int*)d_ws;
  int* tlist  = counts + 16;
  const size_t XOFF = 1u << 20;
  const size_t WOFF = XOFF + (size_t)TOK * DIN * 2;
  const size_t NEED = WOFF + (size_t)NE * DOUT * DIN * 2;

  hipMemsetAsync(counts, 0, 16 * sizeof(int), stream);

  if (ws_size >= NEED) {
    unsigned short* xbf = (unsigned short*)((char*)d_ws + XOFF);
    unsigned short* wbf = (unsigned short*)((char*)d_ws + WOFF);
    gate_convert<<<TOK / 4, 256, 0, stream>>>(x, gw, gb, counts, tlist, xbf);
    convw<<<8192, 256, 0, stream>>>(ew, wbf);
    // 32 n-tiles x (TOK/128 + NE) worst-case slots = 2304 blocks (8 | 2304)
    moe_gemm_bf<<<32 * (TOK / BM + NE), 256, 0, stream>>>(xbf, wbf, eb, counts, tlist, out);
  } else {
    gate_kernel<<<TOK / 4, 256, 0, stream>>>(x, gw, gb, counts, tlist);
    dim3 grid(DOUT / FBM, TOK / FBM + NE, 1);
    moe_gemm<<<grid, 256, 0, stream>>>(x, ew, eb, counts, tlist, out);
  }
}

// Round 6
// 671.611 us; speedup vs baseline: 1.2861x; 1.2861x over previous
//
#include <hip/hip_runtime.h>

#define NE   8
#define DIN  4096
#define DOUT 4096
#define TOK  8192

// fast-path tile: 128x128, BK=32, ring-3 LDS pipeline, 3 blocks/CU
#define BM 128
#define BN 128
#define BK 32
#define NT (DIN / BK)       // 128 K-steps
#define BUFE (BM * BK)      // 4096 bf16 elems per operand buffer (8 KB)

// legacy fallback tile
#define FBM 128
#define FBK 32
#define LDSK 40

typedef __attribute__((ext_vector_type(4))) float f32x4;
typedef __attribute__((ext_vector_type(8))) short bf16x8;
typedef __attribute__((ext_vector_type(2))) unsigned long long u64x2;

#define AS1 __attribute__((address_space(1)))
#define AS3 __attribute__((address_space(3)))

static __device__ __forceinline__ unsigned short f2bf(float f) {
  unsigned u = __builtin_bit_cast(unsigned, f);
  u += 0x7fffu + ((u >> 16) & 1u);   // RTNE
  return (unsigned short)(u >> 16);
}

static __device__ __forceinline__ unsigned long long pack4(f32x4 v) {
  return (unsigned long long)f2bf(v[0])
       | ((unsigned long long)f2bf(v[1]) << 16)
       | ((unsigned long long)f2bf(v[2]) << 32)
       | ((unsigned long long)f2bf(v[3]) << 48);
}

static __device__ __forceinline__ void gload16(const void* g, void* l) {
  __builtin_amdgcn_global_load_lds((const AS1 unsigned int*)g,
                                   (AS3 unsigned int*)l, 16, 0, 0);
}

// ---------- fused prep: gating (fp32-exact) + x->bf16  AND  weights->bf16 ----------
__global__ void prep_kernel(const float* __restrict__ x, const float* __restrict__ gw,
                            const float* __restrict__ gb, int* __restrict__ counts,
                            int* __restrict__ tlist, unsigned short* __restrict__ xbf,
                            const float* __restrict__ ew, unsigned short* __restrict__ wbf) {
  if (blockIdx.x < TOK / 4) {
    // ---- gating + x conversion (4 tokens/block, 1 wave/token) ----
    const int lane = threadIdx.x & 63;
    const int tok  = blockIdx.x * 4 + (threadIdx.x >> 6);
    const float* xr = x + (size_t)tok * DIN;
    unsigned short* xo = xbf + (size_t)tok * DIN;
    float acc[NE];
    #pragma unroll
    for (int e = 0; e < NE; ++e) acc[e] = 0.f;
    for (int i = lane * 4; i < DIN; i += 256) {
      f32x4 xv = *(const f32x4*)(xr + i);
      *(unsigned long long*)(xo + i) = pack4(xv);
      #pragma unroll
      for (int e = 0; e < NE; ++e) {
        f32x4 wv = *(const f32x4*)(gw + e * DIN + i);
        acc[e] += xv[0]*wv[0] + xv[1]*wv[1] + xv[2]*wv[2] + xv[3]*wv[3];
      }
    }
    #pragma unroll
    for (int e = 0; e < NE; ++e) {
      float v = acc[e];
      #pragma unroll
      for (int o = 32; o > 0; o >>= 1) v += __shfl_xor(v, o);
      acc[e] = v;
    }
    if (lane == 0) {
      float bv = acc[0] + gb[0];
      int best = 0;
      #pragma unroll
      for (int e = 1; e < NE; ++e) {
        float v = acc[e] + gb[e];
        if (v > bv) { bv = v; best = e; }   // strict > == numpy first-max
      }
      int pos = atomicAdd(&counts[best], 1);
      tlist[best * TOK + pos] = tok;
    }
  } else {
    // ---- expert weights fp32 -> bf16 (8192 blocks, grid-stride) ----
    const int bid = blockIdx.x - TOK / 4;
    const size_t n = (size_t)NE * DOUT * DIN;
    size_t idx = ((size_t)bid * 256 + threadIdx.x) * 8;
    const size_t stride = (size_t)8192 * 256 * 8;
    for (; idx < n; idx += stride) {
      f32x4 a = *(const f32x4*)(ew + idx);
      f32x4 b = *(const f32x4*)(ew + idx + 4);
      u64x2 v; v[0] = pack4(a); v[1] = pack4(b);
      *(u64x2*)(wbf + idx) = v;
    }
  }
}

// ---------- fast grouped GEMM: 128x128, BK=32, ring-3, counted vmcnt ----------
// Sync invariants (structure validated in round 5; swizzle corrected here):
//   stage(t) at step t-2 -> buf[t%3]; after step t-1's vmcnt(4)+barrier the
//   ONLY possibly-outstanding stage is (t+1)'s => tile t collectively landed.
//   stage(t+2) at step t overwrites buf[(t+2)%3] = tile t-1, whose ds_reads
//   completed before step t-1's barrier (lgkmcnt before MFMA + barrier).
//   vmcnt never drains to 0 in-loop; ONE barrier per step.
// Bank math (BK=32 => 64-B rows, 4x16B slots): slot = lk ^ ((r>>2)&3) gives
//   bank-group (4(r&1) + lk^((r>>2)&3)) mod 8: all 8 groups exactly 2x per
//   16-lane quarter => 2-way (free). Same involution pre-applied to the
//   global source column (rule #21 both-sides).
__global__ __launch_bounds__(256, 3)
void moe_gemm_bf(const unsigned short* __restrict__ xbf,
                 const unsigned short* __restrict__ wbf,
                 const float* __restrict__ eb,
                 const int* __restrict__ counts,
                 const int* __restrict__ tlist,
                 float* __restrict__ out) {
  __shared__ unsigned short sA[3][BUFE];   // 24 KB
  __shared__ unsigned short sB[3][BUFE];   // 24 KB
  __shared__ int rowtok[BM];

  const int tid = threadIdx.x;

  // XCD-chunked bijective swizzle: 2304 = 8 * 288; slot-major so one XCD runs
  // complete n-sweeps of ~9 slots (~1 expert): A-panels L2-resident per XCD
  const int cpx  = gridDim.x >> 3;
  const int wgid = ((int)blockIdx.x & 7) * cpx + ((int)blockIdx.x >> 3);
  const int ntile = wgid & 31;
  const int slot  = wgid >> 5;

  int e = -1, mtile = 0, Me = 0;
  {
    int accn = 0;
    #pragma unroll
    for (int j = 0; j < NE; ++j) {
      int c = counts[j];
      int tt = (c + BM - 1) / BM;
      if (e < 0 && slot < accn + tt) { e = j; mtile = slot - accn; Me = c; }
      accn += tt;
    }
  }
  if (e < 0) return;

  const int n0 = ntile * BN;
  const int m0 = mtile * BM;
  const unsigned short* wbase = wbf + (size_t)e * DOUT * DIN;

  if (tid < BM) {
    int r = m0 + tid;
    rowtok[tid] = tlist[e * TOK + (r < Me ? r : Me - 1)];
  }
  __syncthreads();

  const int w = tid >> 6, l = tid & 63;

  // ---- staging geometry: thread -> (row srow/srow+64, 16B slot sslot)
  // source col pre-swizzled by f(r) = (r>>2)&3  [f(srow+64) == f(srow)]
  const int srow  = tid >> 2;          // 0..63
  const int sslot = tid & 3;
  const int colsw = (sslot ^ ((srow >> 2) & 3)) * 8;   // elems

  const unsigned short* ga0 = xbf   + (size_t)rowtok[srow]      * DIN + colsw;
  const unsigned short* ga1 = xbf   + (size_t)rowtok[srow + 64] * DIN + colsw;
  const unsigned short* gb0 = wbase + (size_t)(n0 + srow)       * DIN + colsw;
  const unsigned short* gb1 = wbase + (size_t)(n0 + srow + 64)  * DIN + colsw;
  const int ldsb = w * 512;            // wave-uniform base (elems) within a 4KB half

  // ---- frag geometry: 4 waves as 2x2, per-wave 64x64 out
  const int wr = (w >> 1) * 64;
  const int wc = (w & 1) * 64;
  const int lr = l & 15, lk = l >> 4;
  int offA[4], offB[4];
  #pragma unroll
  for (int m = 0; m < 4; ++m) {
    int r = wr + m * 16 + lr;
    offA[m] = r * BK + ((lk ^ ((r >> 2) & 3)) * 8);
  }
  #pragma unroll
  for (int n = 0; n < 4; ++n) {
    int r = wc + n * 16 + lr;
    offB[n] = r * BK + ((lk ^ ((r >> 2) & 3)) * 8);
  }

  f32x4 acc[4][4];
  #pragma unroll
  for (int m = 0; m < 4; ++m)
    #pragma unroll
    for (int n = 0; n < 4; ++n) acc[m][n] = (f32x4){0.f, 0.f, 0.f, 0.f};

#define STAGE(kt, b) do {                                   \
    const int ko_ = (kt) * BK;                              \
    gload16(ga0 + ko_, &sA[b][ldsb]);                       \
    gload16(ga1 + ko_, &sA[b][2048 + ldsb]);                \
    gload16(gb0 + ko_, &sB[b][ldsb]);                       \
    gload16(gb1 + ko_, &sB[b][2048 + ldsb]);                \
  } while (0)

  // prologue: tiles 0,1 in flight (8 loads); vmcnt(4) => tile 0 landed
  STAGE(0, 0);
  STAGE(1, 1);
  asm volatile("s_waitcnt vmcnt(4)" ::: "memory");
  __builtin_amdgcn_s_barrier();
  asm volatile("" ::: "memory");

  int bc = 0, bs = 2;
  for (int t = 0; t < NT; ++t) {
    const int ts = (t + 2 < NT) ? t + 2 : NT - 1;   // clamped tail: never read
    STAGE(ts, bs);

    bf16x8 av[4], bv[4];
    #pragma unroll
    for (int m = 0; m < 4; ++m) av[m] = *(const bf16x8*)&sA[bc][offA[m]];
    #pragma unroll
    for (int n = 0; n < 4; ++n) bv[n] = *(const bf16x8*)&sB[bc][offB[n]];

    __builtin_amdgcn_s_setprio(1);
    #pragma unroll
    for (int m = 0; m < 4; ++m)
      #pragma unroll
      for (int n = 0; n < 4; ++n)
        acc[m][n] = __builtin_amdgcn_mfma_f32_16x16x32_bf16(av[m], bv[n], acc[m][n], 0, 0, 0);
    __builtin_amdgcn_s_setprio(0);

    asm volatile("s_waitcnt vmcnt(4)" ::: "memory");   // tile t+1 landed; t+2 in flight
    __builtin_amdgcn_s_barrier();
    asm volatile("" ::: "memory");

    bc = (bc == 2) ? 0 : bc + 1;
    bs = (bs == 2) ? 0 : bs + 1;
  }

  // epilogue: bias + guarded scatter (C/D: col = lane&15, row = (lane>>4)*4 + j)
  float bias[4];
  #pragma unroll
  for (int n = 0; n < 4; ++n) bias[n] = eb[e * DOUT + n0 + wc + n * 16 + lr];

  #pragma unroll
  for (int m = 0; m < 4; ++m) {
    #pragma unroll
    for (int j = 0; j < 4; ++j) {
      int rloc = wr + m * 16 + lk * 4 + j;
      if (m0 + rloc < Me) {
        int tokr = rowtok[rloc];
        float* op = out + (size_t)tokr * DOUT + n0 + wc;
        #pragma unroll
        for (int n = 0; n < 4; ++n)
          op[n * 16 + lr] = acc[m][n][j] + bias[n];
      }
    }
  }
#undef STAGE
}

// ================= legacy fallback (fp32 direct, used only if ws too small) ==========
__global__ void gate_kernel(const float* __restrict__ x, const float* __restrict__ gw,
                            const float* __restrict__ gb, int* __restrict__ counts,
                            int* __restrict__ tlist) {
  const int lane = threadIdx.x & 63;
  const int tok  = blockIdx.x * 4 + (threadIdx.x >> 6);
  const float* xr = x + (size_t)tok * DIN;
  float acc[NE];
  #pragma unroll
  for (int e = 0; e < NE; ++e) acc[e] = 0.f;
  for (int i = lane; i < DIN; i += 64) {
    float xv = xr[i];
    #pragma unroll
    for (int e = 0; e < NE; ++e) acc[e] += xv * gw[e * DIN + i];
  }
  #pragma unroll
  for (int e = 0; e < NE; ++e) {
    float v = acc[e];
    #pragma unroll
    for (int o = 32; o > 0; o >>= 1) v += __shfl_xor(v, o);
    acc[e] = v;
  }
  if (lane == 0) {
    float bv = acc[0] + gb[0];
    int best = 0;
    #pragma unroll
    for (int e = 1; e < NE; ++e) {
      float v = acc[e] + gb[e];
      if (v > bv) { bv = v; best = e; }
    }
    int pos = atomicAdd(&counts[best], 1);
    tlist[best * TOK + pos] = tok;
  }
}

__global__ __launch_bounds__(256, 2)
void moe_gemm(const float* __restrict__ x, const float* __restrict__ ew,
              const float* __restrict__ eb, const int* __restrict__ counts,
              const int* __restrict__ tlist, float* __restrict__ out) {
  __shared__ unsigned short fA[2][FBM * LDSK];
  __shared__ unsigned short fB[2][FBM * LDSK];
  __shared__ int rowtok[FBM];

  const int tid  = threadIdx.x;
  const int slot = blockIdx.y;

  int e = -1, mtile = 0, Me = 0;
  {
    int acc = 0;
    #pragma unroll
    for (int j = 0; j < NE; ++j) {
      int c = counts[j];
      int t = (c + FBM - 1) / FBM;
      if (e < 0 && slot < acc + t) { e = j; mtile = slot - acc; Me = c; }
      acc += t;
    }
  }
  if (e < 0) return;

  const int n0 = blockIdx.x * FBM;
  const int m0 = mtile * FBM;
  const float* we = ew + (size_t)e * DOUT * DIN;

  if (tid < FBM) {
    int r = m0 + tid;
    rowtok[tid] = tlist[e * TOK + (r < Me ? r : Me - 1)];
  }
  __syncthreads();

  const int srow = tid >> 3;
  const int scol = (tid & 7) * 4;
  const int lane = tid & 63;
  const int w  = tid >> 6;
  const int wr = (w >> 1) * 64;
  const int wc = (w & 1) * 64;
  const int lr = lane & 15;
  const int lk = lane >> 4;

  f32x4 accf[4][4];
  #pragma unroll
  for (int m = 0; m < 4; ++m)
    #pragma unroll
    for (int n = 0; n < 4; ++n) accf[m][n] = (f32x4){0.f, 0.f, 0.f, 0.f};

  const float* aptr[4];
  const float* bptr[4];
  #pragma unroll
  for (int p = 0; p < 4; ++p) {
    int r = p * 32 + srow;
    aptr[p] = x  + (size_t)rowtok[r] * DIN + scol;
    bptr[p] = we + (size_t)(n0 + r)  * DIN + scol;
  }

  #pragma unroll
  for (int p = 0; p < 4; ++p) {
    int r = p * 32 + srow;
    *(unsigned long long*)&fA[0][r * LDSK + scol] = pack4(*(const f32x4*)(aptr[p]));
    *(unsigned long long*)&fB[0][r * LDSK + scol] = pack4(*(const f32x4*)(bptr[p]));
  }
  __syncthreads();

  int cur = 0;
  for (int kt = 0; kt < DIN / FBK; ++kt) {
    f32x4 ra[4], rb[4];
    const bool more = (kt + 1 < DIN / FBK);
    if (more) {
      const int koff = (kt + 1) * FBK;
      #pragma unroll
      for (int p = 0; p < 4; ++p) {
        ra[p] = *(const f32x4*)(aptr[p] + koff);
        rb[p] = *(const f32x4*)(bptr[p] + koff);
      }
    }
    bf16x8 af[4], bfr[4];
    #pragma unroll
    for (int m = 0; m < 4; ++m)
      af[m] = *(const bf16x8*)&fA[cur][(wr + m * 16 + lr) * LDSK + lk * 8];
    #pragma unroll
    for (int n = 0; n < 4; ++n)
      bfr[n] = *(const bf16x8*)&fB[cur][(wc + n * 16 + lr) * LDSK + lk * 8];
    #pragma unroll
    for (int m = 0; m < 4; ++m)
      #pragma unroll
      for (int n = 0; n < 4; ++n)
        accf[m][n] = __builtin_amdgcn_mfma_f32_16x16x32_bf16(af[m], bfr[n], accf[m][n], 0, 0, 0);
    if (more) {
      #pragma unroll
      for (int p = 0; p < 4; ++p) {
        int r = p * 32 + srow;
        *(unsigned long long*)&fA[cur ^ 1][r * LDSK + scol] = pack4(ra[p]);
        *(unsigned long long*)&fB[cur ^ 1][r * LDSK + scol] = pack4(rb[p]);
      }
    }
    __syncthreads();
    cur ^= 1;
  }

  float bias[4];
  #pragma unroll
  for (int n = 0; n < 4; ++n) bias[n] = eb[e * DOUT + n0 + wc + n * 16 + lr];

  #pragma unroll
  for (int m = 0; m < 4; ++m) {
    #pragma unroll
    for (int j = 0; j < 4; ++j) {
      int rloc = wr + m * 16 + lk * 4 + j;
      if (m0 + rloc < Me) {
        int tokr = rowtok[rloc];
        float* op = out + (size_t)tokr * DOUT + n0 + wc;
        #pragma unroll
        for (int n = 0; n < 4; ++n)
          op[n * 16 + lr] = accf[m][n][j] + bias[n];
      }
    }
  }
}

extern "C" void kernel_launch(void* const* d_in, const int* in_sizes, int n_in,
                              void* d_out, int out_size, void* d_ws, size_t ws_size,
                              hipStream_t stream) {
  const float* x  = (const float*)d_in[0];
  const float* gw = (const float*)d_in[1];
  const float* gb = (const float*)d_in[2];
  const float* ew = (const float*)d_in[3];
  const float* eb = (const float*)d_in[4];
  float* out = (float*)d_out;

  // ws layout: counts[16] | tlist[8*8192] | @1MB xbf (64MB) | wbf (256MB)
  int* counts = (int*)d_ws;
  int* tlist  = counts + 16;
  const size_t XOFF = 1u << 20;
  const size_t WOFF = XOFF + (size_t)TOK * DIN * 2;
  const size_t NEED = WOFF + (size_t)NE * DOUT * DIN * 2;

  hipMemsetAsync(counts, 0, 16 * sizeof(int), stream);

  if (ws_size >= NEED) {
    unsigned short* xbf = (unsigned short*)((char*)d_ws + XOFF);
    unsigned short* wbf = (unsigned short*)((char*)d_ws + WOFF);
    prep_kernel<<<TOK / 4 + 8192, 256, 0, stream>>>(x, gw, gb, counts, tlist, xbf, ew, wbf);
    // 32 n-tiles x (TOK/128 + NE) worst-case slots = 2304 blocks (8 | 2304)
    moe_gemm_bf<<<32 * (TOK / BM + NE), 256, 0, stream>>>(xbf, wbf, eb, counts, tlist, out);
  } else {
    gate_kernel<<<TOK / 4, 256, 0, stream>>>(x, gw, gb, counts, tlist);
    dim3 grid(DOUT / FBM, TOK / FBM + NE, 1);
    moe_gemm<<<grid, 256, 0, stream>>>(x, ew, eb, counts, tlist, out);
  }
}

// Round 7
// 575.344 us; speedup vs baseline: 1.5013x; 1.1673x over previous
//
#include <hip/hip_runtime.h>

#define NE   8
#define DIN  4096
#define DOUT 4096
#define TOK  8192

#define BM 128
#define BN 128
#define BKF 64    // fast-path K-step (bf16 elems)

// legacy fallback tile params
#define BK 32
#define LDSK 40

typedef __attribute__((ext_vector_type(4))) float f32x4;
typedef __attribute__((ext_vector_type(8))) short bf16x8;
typedef __attribute__((ext_vector_type(2))) unsigned long long u64x2;

#define AS1 __attribute__((address_space(1)))
#define AS3 __attribute__((address_space(3)))

static __device__ __forceinline__ unsigned short f2bf(float f) {
  unsigned u = __builtin_bit_cast(unsigned, f);
  u += 0x7fffu + ((u >> 16) & 1u);   // RTNE
  return (unsigned short)(u >> 16);
}

static __device__ __forceinline__ unsigned long long pack4(f32x4 v) {
  return (unsigned long long)f2bf(v[0])
       | ((unsigned long long)f2bf(v[1]) << 16)
       | ((unsigned long long)f2bf(v[2]) << 32)
       | ((unsigned long long)f2bf(v[3]) << 48);
}

static __device__ __forceinline__ void gload16(const void* g, void* l) {
  __builtin_amdgcn_global_load_lds((const AS1 unsigned int*)g,
                                   (AS3 unsigned int*)l, 16, 0, 0);
}

// ---------- fused prep: gating (fp32-exact) + x->bf16  AND  weights->bf16 ----------
__global__ void prep_kernel(const float* __restrict__ x, const float* __restrict__ gw,
                            const float* __restrict__ gb, int* __restrict__ counts,
                            int* __restrict__ tlist, unsigned short* __restrict__ xbf,
                            const float* __restrict__ ew, unsigned short* __restrict__ wbf) {
  if (blockIdx.x < TOK / 4) {
    // ---- gating + x conversion (4 tokens/block, 1 wave/token) ----
    const int lane = threadIdx.x & 63;
    const int tok  = blockIdx.x * 4 + (threadIdx.x >> 6);
    const float* xr = x + (size_t)tok * DIN;
    unsigned short* xo = xbf + (size_t)tok * DIN;
    float acc[NE];
    #pragma unroll
    for (int e = 0; e < NE; ++e) acc[e] = 0.f;
    for (int i = lane * 4; i < DIN; i += 256) {
      f32x4 xv = *(const f32x4*)(xr + i);
      *(unsigned long long*)(xo + i) = pack4(xv);
      #pragma unroll
      for (int e = 0; e < NE; ++e) {
        f32x4 wv = *(const f32x4*)(gw + e * DIN + i);
        acc[e] += xv[0]*wv[0] + xv[1]*wv[1] + xv[2]*wv[2] + xv[3]*wv[3];
      }
    }
    #pragma unroll
    for (int e = 0; e < NE; ++e) {
      float v = acc[e];
      #pragma unroll
      for (int o = 32; o > 0; o >>= 1) v += __shfl_xor(v, o);
      acc[e] = v;
    }
    if (lane == 0) {
      float bv = acc[0] + gb[0];
      int best = 0;
      #pragma unroll
      for (int e = 1; e < NE; ++e) {
        float v = acc[e] + gb[e];
        if (v > bv) { bv = v; best = e; }   // strict > == numpy first-max
      }
      int pos = atomicAdd(&counts[best], 1);
      tlist[best * TOK + pos] = tok;
    }
  } else {
    // ---- expert weights fp32 -> bf16 (8192 blocks, grid-stride) ----
    const int bid = blockIdx.x - TOK / 4;
    const size_t n = (size_t)NE * DOUT * DIN;
    size_t idx = ((size_t)bid * 256 + threadIdx.x) * 8;
    const size_t stride = (size_t)8192 * 256 * 8;
    for (; idx < n; idx += stride) {
      f32x4 a = *(const f32x4*)(ew + idx);
      f32x4 b = *(const f32x4*)(ew + idx + 4);
      u64x2 v; v[0] = pack4(a); v[1] = pack4(b);
      *(u64x2*)(wbf + idx) = v;
    }
  }
}

// ---------- fast grouped GEMM: bf16 inputs, global_load_lds staging ----------
// (round-2 proven configuration: 128x128, BK=64, single-buffer 2-barrier loop,
//  806 TF effective, MfmaUtil 37%, LDS bank conflicts == 0)
__global__ __launch_bounds__(256, 2)
void moe_gemm_bf(const unsigned short* __restrict__ xbf,
                 const unsigned short* __restrict__ wbf,
                 const float* __restrict__ eb,
                 const int* __restrict__ counts,
                 const int* __restrict__ tlist,
                 float* __restrict__ out) {
  __shared__ unsigned short sA[BM * BKF];  // 16 KB, linear [128][64]
  __shared__ unsigned short sB[BN * BKF];  // 16 KB
  __shared__ int rowtok[BM];

  const int tid  = threadIdx.x;
  const int slot = blockIdx.y;

  int e = -1, mtile = 0, Me = 0;
  {
    int acc = 0;
    #pragma unroll
    for (int j = 0; j < NE; ++j) {
      int c = counts[j];
      int t = (c + BM - 1) / BM;
      if (e < 0 && slot < acc + t) { e = j; mtile = slot - acc; Me = c; }
      acc += t;
    }
  }
  if (e < 0) return;

  const int n0 = blockIdx.x * BN;
  const int m0 = mtile * BM;

  if (tid < BM) {
    int r = m0 + tid;
    rowtok[tid] = tlist[e * TOK + (r < Me ? r : Me - 1)];
  }
  __syncthreads();

  const int lane = tid & 63;
  const int w    = tid >> 6;
  // staging geometry: each wave chunk c stages 8 rows x 64 cols (1 KB)
  const int j8   = lane & 7;     // 16B slot within row
  const int rsub = lane >> 3;    // row within 8-row chunk
  const int colsw = ((j8 ^ rsub) * 8);  // pre-swizzled global elem offset (T2 involution)

  const unsigned short* ag[4];
  const unsigned short* bg[4];
  const unsigned short* wbase = wbf + (size_t)e * DOUT * DIN;
  #pragma unroll
  for (int c = 0; c < 4; ++c) {
    int row = (w * 4 + c) * 8 + rsub;
    ag[c] = xbf   + (size_t)rowtok[row] * DIN + colsw;
    bg[c] = wbase + (size_t)(n0 + row)  * DIN + colsw;
  }

  const int wr = (w >> 1) * 64;
  const int wc = (w & 1) * 64;
  const int lr = lane & 15;
  const int lk = lane >> 4;
  const int lr7 = lr & 7;

  f32x4 acc[4][4];
  #pragma unroll
  for (int m = 0; m < 4; ++m)
    #pragma unroll
    for (int n = 0; n < 4; ++n) acc[m][n] = (f32x4){0.f, 0.f, 0.f, 0.f};

  for (int kt = 0; kt < DIN / BKF; ++kt) {   // 64 K-tiles
    const int kofs = kt * BKF;
    #pragma unroll
    for (int c = 0; c < 4; ++c) {
      gload16(ag[c] + kofs, &sA[(w * 4 + c) * 512]);
      gload16(bg[c] + kofs, &sB[(w * 4 + c) * 512]);
    }
    __syncthreads();   // drains vmcnt before barrier (compiler-inserted)

    #pragma unroll
    for (int ks = 0; ks < 2; ++ks) {
      bf16x8 af[4], bfv[4];
      #pragma unroll
      for (int m = 0; m < 4; ++m)
        af[m] = *(const bf16x8*)&sA[(wr + m * 16 + lr) * BKF + (((ks * 4 + lk) ^ lr7) * 8)];
      #pragma unroll
      for (int n = 0; n < 4; ++n)
        bfv[n] = *(const bf16x8*)&sB[(wc + n * 16 + lr) * BKF + (((ks * 4 + lk) ^ lr7) * 8)];
      #pragma unroll
      for (int m = 0; m < 4; ++m)
        #pragma unroll
        for (int n = 0; n < 4; ++n)
          acc[m][n] = __builtin_amdgcn_mfma_f32_16x16x32_bf16(af[m], bfv[n], acc[m][n], 0, 0, 0);
    }
    __syncthreads();
  }

  // epilogue: bias + guarded scatter (C/D: col = lane&15, row = (lane>>4)*4 + j)
  float bias[4];
  #pragma unroll
  for (int n = 0; n < 4; ++n) bias[n] = eb[e * DOUT + n0 + wc + n * 16 + lr];

  #pragma unroll
  for (int m = 0; m < 4; ++m) {
    #pragma unroll
    for (int j = 0; j < 4; ++j) {
      int rloc = wr + m * 16 + lk * 4 + j;
      if (m0 + rloc < Me) {
        int tokr = rowtok[rloc];
        float* op = out + (size_t)tokr * DOUT + n0 + wc;
        #pragma unroll
        for (int n = 0; n < 4; ++n)
          op[n * 16 + lr] = acc[m][n][j] + bias[n];
      }
    }
  }
}

// ================= legacy fallback path (used only if ws too small) ==========
__global__ void gate_kernel(const float* __restrict__ x, const float* __restrict__ gw,
                            const float* __restrict__ gb, int* __restrict__ counts,
                            int* __restrict__ tlist) {
  const int lane = threadIdx.x & 63;
  const int tok  = blockIdx.x * 4 + (threadIdx.x >> 6);
  const float* xr = x + (size_t)tok * DIN;
  float acc[NE];
  #pragma unroll
  for (int e = 0; e < NE; ++e) acc[e] = 0.f;
  for (int i = lane; i < DIN; i += 64) {
    float xv = xr[i];
    #pragma unroll
    for (int e = 0; e < NE; ++e) acc[e] += xv * gw[e * DIN + i];
  }
  #pragma unroll
  for (int e = 0; e < NE; ++e) {
    float v = acc[e];
    #pragma unroll
    for (int o = 32; o > 0; o >>= 1) v += __shfl_xor(v, o);
    acc[e] = v;
  }
  if (lane == 0) {
    float bv = acc[0] + gb[0];
    int best = 0;
    #pragma unroll
    for (int e = 1; e < NE; ++e) {
      float v = acc[e] + gb[e];
      if (v > bv) { bv = v; best = e; }
    }
    int pos = atomicAdd(&counts[best], 1);
    tlist[best * TOK + pos] = tok;
  }
}

__global__ __launch_bounds__(256, 2)
void moe_gemm(const float* __restrict__ x, const float* __restrict__ ew,
              const float* __restrict__ eb, const int* __restrict__ counts,
              const int* __restrict__ tlist, float* __restrict__ out) {
  __shared__ unsigned short fA[2][BM * LDSK];
  __shared__ unsigned short fB[2][BM * LDSK];
  __shared__ int rowtok[BM];

  const int tid  = threadIdx.x;
  const int slot = blockIdx.y;

  int e = -1, mtile = 0, Me = 0;
  {
    int acc = 0;
    #pragma unroll
    for (int j = 0; j < NE; ++j) {
      int c = counts[j];
      int t = (c + BM - 1) / BM;
      if (e < 0 && slot < acc + t) { e = j; mtile = slot - acc; Me = c; }
      acc += t;
    }
  }
  if (e < 0) return;

  const int n0 = blockIdx.x * BM;
  const int m0 = mtile * BM;
  const float* we = ew + (size_t)e * DOUT * DIN;

  if (tid < BM) {
    int r = m0 + tid;
    rowtok[tid] = tlist[e * TOK + (r < Me ? r : Me - 1)];
  }
  __syncthreads();

  const int srow = tid >> 3;
  const int scol = (tid & 7) * 4;
  const int lane = tid & 63;
  const int w  = tid >> 6;
  const int wr = (w >> 1) * 64;
  const int wc = (w & 1) * 64;
  const int lr = lane & 15;
  const int lk = lane >> 4;

  f32x4 accf[4][4];
  #pragma unroll
  for (int m = 0; m < 4; ++m)
    #pragma unroll
    for (int n = 0; n < 4; ++n) accf[m][n] = (f32x4){0.f, 0.f, 0.f, 0.f};

  const float* aptr[4];
  const float* bptr[4];
  #pragma unroll
  for (int p = 0; p < 4; ++p) {
    int r = p * 32 + srow;
    aptr[p] = x  + (size_t)rowtok[r] * DIN + scol;
    bptr[p] = we + (size_t)(n0 + r)  * DIN + scol;
  }

  #pragma unroll
  for (int p = 0; p < 4; ++p) {
    int r = p * 32 + srow;
    *(unsigned long long*)&fA[0][r * LDSK + scol] = pack4(*(const f32x4*)(aptr[p]));
    *(unsigned long long*)&fB[0][r * LDSK + scol] = pack4(*(const f32x4*)(bptr[p]));
  }
  __syncthreads();

  int cur = 0;
  for (int kt = 0; kt < DIN / BK; ++kt) {
    f32x4 ra[4], rb[4];
    const bool more = (kt + 1 < DIN / BK);
    if (more) {
      const int koff = (kt + 1) * BK;
      #pragma unroll
      for (int p = 0; p < 4; ++p) {
        ra[p] = *(const f32x4*)(aptr[p] + koff);
        rb[p] = *(const f32x4*)(bptr[p] + koff);
      }
    }
    bf16x8 af[4], bfr[4];
    #pragma unroll
    for (int m = 0; m < 4; ++m)
      af[m] = *(const bf16x8*)&fA[cur][(wr + m * 16 + lr) * LDSK + lk * 8];
    #pragma unroll
    for (int n = 0; n < 4; ++n)
      bfr[n] = *(const bf16x8*)&fB[cur][(wc + n * 16 + lr) * LDSK + lk * 8];
    #pragma unroll
    for (int m = 0; m < 4; ++m)
      #pragma unroll
      for (int n = 0; n < 4; ++n)
        accf[m][n] = __builtin_amdgcn_mfma_f32_16x16x32_bf16(af[m], bfr[n], accf[m][n], 0, 0, 0);
    if (more) {
      #pragma unroll
      for (int p = 0; p < 4; ++p) {
        int r = p * 32 + srow;
        *(unsigned long long*)&fA[cur ^ 1][r * LDSK + scol] = pack4(ra[p]);
        *(unsigned long long*)&fB[cur ^ 1][r * LDSK + scol] = pack4(rb[p]);
      }
    }
    __syncthreads();
    cur ^= 1;
  }

  float bias[4];
  #pragma unroll
  for (int n = 0; n < 4; ++n) bias[n] = eb[e * DOUT + n0 + wc + n * 16 + lr];

  #pragma unroll
  for (int m = 0; m < 4; ++m) {
    #pragma unroll
    for (int j = 0; j < 4; ++j) {
      int rloc = wr + m * 16 + lk * 4 + j;
      if (m0 + rloc < Me) {
        int tokr = rowtok[rloc];
        float* op = out + (size_t)tokr * DOUT + n0 + wc;
        #pragma unroll
        for (int n = 0; n < 4; ++n)
          op[n * 16 + lr] = accf[m][n][j] + bias[n];
      }
    }
  }
}

extern "C" void kernel_launch(void* const* d_in, const int* in_sizes, int n_in,
                              void* d_out, int out_size, void* d_ws, size_t ws_size,
                              hipStream_t stream) {
  const float* x  = (const float*)d_in[0];
  const float* gw = (const float*)d_in[1];
  const float* gb = (const float*)d_in[2];
  const float* ew = (const float*)d_in[3];
  const float* eb = (const float*)d_in[4];
  float* out = (float*)d_out;

  // ws layout: counts[16] | tlist[8*8192] | @1MB xbf (64MB) | wbf (256MB)
  int* counts = (int*)d_ws;
  int* tlist  = counts + 16;
  const size_t XOFF = 1u << 20;
  const size_t WOFF = XOFF + (size_t)TOK * DIN * 2;
  const size_t NEED = WOFF + (size_t)NE * DOUT * DIN * 2;

  hipMemsetAsync(counts, 0, 16 * sizeof(int), stream);

  if (ws_size >= NEED) {
    unsigned short* xbf = (unsigned short*)((char*)d_ws + XOFF);
    unsigned short* wbf = (unsigned short*)((char*)d_ws + WOFF);
    prep_kernel<<<TOK / 4 + 8192, 256, 0, stream>>>(x, gw, gb, counts, tlist, xbf, ew, wbf);
    dim3 grid(DOUT / BN, TOK / BM + NE, 1);   // 32 n-tiles x 72 worst-case m-slots
    moe_gemm_bf<<<grid, 256, 0, stream>>>(xbf, wbf, eb, counts, tlist, out);
  } else {
    gate_kernel<<<TOK / 4, 256, 0, stream>>>(x, gw, gb, counts, tlist);
    dim3 grid(DOUT / BM, TOK / BM + NE, 1);
    moe_gemm<<<grid, 256, 0, stream>>>(x, ew, eb, counts, tlist, out);
  }
}